// Round 16
// baseline (10056.115 us; speedup 1.0000x reference)
//
#include <hip/hip_runtime.h>
#include <cstddef>

#define NMAT 512
#define MRHS 12

__device__ __forceinline__ float rdlane(float v, int l) {
    return __int_as_float(__builtin_amdgcn_readlane(__float_as_int(v), l));
}

// ---------------- Stage 1: A = LU = constant_part + sum_e r[e] * M[e] ----------------
__global__ void __launch_bounds__(256) k_setup(const float* __restrict__ M,
                                               const float* __restrict__ r,
                                               const float* __restrict__ cpart,
                                               float* __restrict__ A,
                                               float* __restrict__ LU) {
    __shared__ float rs[1024];
    const int tid = threadIdx.x;
    for (int i = tid; i < 1024; i += 256) rs[i] = r[i];
    __syncthreads();
    const int idx2 = blockIdx.x * 256 + tid;          // 0..131071
    const float2* __restrict__ M2 = (const float2*)M;
    float2 a = ((const float2*)cpart)[idx2];
    float ax = a.x, ay = a.y;
#pragma unroll 16
    for (int e = 0; e < 1024; ++e) {
        float2 v = M2[(size_t)e * 131072u + idx2];
        float rv = rs[e];
        ax += rv * v.x; ay += rv * v.y;
    }
    float2 o; o.x = ax; o.y = ay;
    ((float2*)A)[idx2] = o;
    ((float2*)LU)[idx2] = o;
}

// ---------------- panel body (R12-proven VERBATIM: 8 waves, 512 thr) ----------------
// Diag 64x64: row i on wave (i&7) slot (i>>3), lane = column; rank-1 with pivot-row LDS
// broadcast. L21 rows: lane = row, left-looking substitution, U11 via LDS + const rdlane.
// Writes transposed packed panel into LUT rows [k0,k0+64) and dinvG. LU untouched.
__device__ __forceinline__ void panel_body(const float* __restrict__ LU,
                                           float* __restrict__ LUT,
                                           float* __restrict__ dinvG,
                                           int k0, int NG,
                                           int w, int lane, int tid,
                                           float (*piv)[64], float* U11lds, float* dinvLDS) {
    const int k1 = k0 + 64;
    float colreg[64];
    if (NG > 0 && w < NG) {
#pragma unroll
        for (int c = 0; c < 64; ++c)
            colreg[c] = LU[(size_t)(k1 + w * 64 + lane) * NMAT + k0 + c];
    }
    float dreg[8];
#pragma unroll
    for (int s = 0; s < 8; ++s)
        dreg[s] = LU[(size_t)(k0 + s * 8 + w) * NMAT + k0 + lane];

    for (int j = 0; j < 64; ++j) {
        if (w == (j & 7)) {
#pragma unroll
            for (int s = 0; s < 8; ++s)
                if ((j >> 3) == s) {
                    piv[j & 1][lane] = dreg[s];
                    U11lds[j * 65 + lane] = dreg[s];
                }
        }
        __syncthreads();
        float pvl = piv[j & 1][lane];
        float pj = __shfl(pvl, j);
        float pinv = 1.0f / pj;
        if (tid == 0) dinvLDS[j] = pinv;
#pragma unroll
        for (int s = 0; s < 8; ++s) {
            int i = s * 8 + w;
            if (i > j) {                        // wave-uniform
                float rv = dreg[s];
                float l = __shfl(rv, j) * pinv;
                float upd = rv - l * pvl;
                rv = (lane > j) ? upd : rv;
                rv = (lane == j) ? l : rv;
                dreg[s] = rv;
            }
        }
    }
    __syncthreads();
    if (w == 0) dinvG[k0 + lane] = dinvLDS[lane];
#pragma unroll
    for (int q = 0; q < 8; ++q) {
        int c = w * 8 + q;
        LUT[(size_t)(k0 + c) * NMAT + k0 + lane] = U11lds[lane * 65 + c];
    }
    if (NG > 0 && w < NG) {
#pragma unroll
        for (int j = 0; j < 64; ++j) {
            float lj = colreg[j] * dinvLDS[j];
            colreg[j] = lj;
            float rowv = U11lds[j * 65 + lane];
#pragma unroll
            for (int jj = j + 1; jj < 64; ++jj)
                colreg[jj] -= lj * rdlane(rowv, jj);
        }
#pragma unroll
        for (int c = 0; c < 64; ++c)
            LUT[(size_t)(k0 + c) * NMAT + k1 + w * 64 + lane] = colreg[c];
    }
}

// ---------------- blocked solves + residual (R11/R13-proven VERBATIM) ----------------
__device__ __forceinline__ void solve0_f(const float* __restrict__ LUT,
                                         const float* __restrict__ dinv,
                                         float* __restrict__ W, int c, int lane) {
    float y[8];
#pragma unroll
    for (int s = 0; s < 8; ++s) y[s] = 0.f;
    y[7] = (lane == 52 + c) ? 1.0f : 0.0f;
    float Dc[64];
#pragma unroll
    for (int q = 0; q < 64; ++q)
        Dc[q] = LUT[(size_t)(448 + q) * NMAT + 448 + lane];
#pragma unroll 4
    for (int jl = 52; jl < 63; ++jl) {
        float yj = __shfl(y[7], jl);
        if (lane > jl) y[7] -= Dc[jl] * yj;
    }
#pragma unroll
    for (int js = 7; js >= 0; --js) {
        const int base = js * 64;
        float a0 = 0.f, a1 = 0.f;
        for (int s = js + 1; s < 8; ++s) {
#pragma unroll 8
            for (int m = 0; m < 64; m += 2) {
                a0 += LUT[(size_t)(s * 64 + m)     * NMAT + base + lane] * rdlane(y[s], m);
                a1 += LUT[(size_t)(s * 64 + m + 1) * NMAT + base + lane] * rdlane(y[s], m + 1);
            }
        }
        y[js] -= (a0 + a1);
#pragma unroll
        for (int q = 0; q < 64; ++q)
            Dc[q] = LUT[(size_t)(base + q) * NMAT + base + lane];
        float dvb = dinv[base + lane];
#pragma unroll 4
        for (int jl = 63; jl >= 0; --jl) {
            float xj = __shfl(y[js], jl) * rdlane(dvb, jl);
            float t = y[js] - Dc[jl] * xj;
            y[js] = (lane < jl) ? t : ((lane == jl) ? xj : y[js]);
        }
    }
#pragma unroll
    for (int s = 0; s < 8; ++s)
        W[(s * 64 + lane) * MRHS + c] = y[s];
}

__device__ __forceinline__ void solve1_f(const float* __restrict__ LUT,
                                         const float* __restrict__ dinv,
                                         const float* __restrict__ B,
                                         float* __restrict__ W, int c, int lane) {
    float y[8];
    float Dc[64];
#pragma unroll
    for (int s = 0; s < 8; ++s) y[s] = B[(s * 64 + lane) * MRHS + c];
#pragma unroll
    for (int js = 0; js < 8; ++js) {
        const int base = js * 64;
        float a0 = 0.f, a1 = 0.f;
        for (int s = 0; s < js; ++s) {
#pragma unroll 8
            for (int m = 0; m < 64; m += 2) {
                a0 += LUT[(size_t)(s * 64 + m)     * NMAT + base + lane] * rdlane(y[s], m);
                a1 += LUT[(size_t)(s * 64 + m + 1) * NMAT + base + lane] * rdlane(y[s], m + 1);
            }
        }
        y[js] -= (a0 + a1);
#pragma unroll
        for (int q = 0; q < 64; ++q)
            Dc[q] = LUT[(size_t)(base + q) * NMAT + base + lane];
#pragma unroll 4
        for (int jl = 0; jl < 63; ++jl) {
            float yj = __shfl(y[js], jl);
            if (lane > jl) y[js] -= Dc[jl] * yj;
        }
    }
#pragma unroll
    for (int js = 7; js >= 0; --js) {
        const int base = js * 64;
        float a0 = 0.f, a1 = 0.f;
        for (int s = js + 1; s < 8; ++s) {
#pragma unroll 8
            for (int m = 0; m < 64; m += 2) {
                a0 += LUT[(size_t)(s * 64 + m)     * NMAT + base + lane] * rdlane(y[s], m);
                a1 += LUT[(size_t)(s * 64 + m + 1) * NMAT + base + lane] * rdlane(y[s], m + 1);
            }
        }
        y[js] -= (a0 + a1);
#pragma unroll
        for (int q = 0; q < 64; ++q)
            Dc[q] = LUT[(size_t)(base + q) * NMAT + base + lane];
        float dvb = dinv[base + lane];
#pragma unroll 4
        for (int jl = 63; jl >= 0; --jl) {
            float xj = __shfl(y[js], jl) * rdlane(dvb, jl);
            float t = y[js] - Dc[jl] * xj;
            y[js] = (lane < jl) ? t : ((lane == jl) ? xj : y[js]);
        }
    }
#pragma unroll
    for (int s = 0; s < 8; ++s)
        W[(s * 64 + lane) * MRHS + c] += y[s];
}

__device__ __forceinline__ void resid_f(const float* __restrict__ A,
                                        const float* __restrict__ W,
                                        float* __restrict__ R, int row, int lane) {
    double acc[MRHS];
#pragma unroll
    for (int cc = 0; cc < MRHS; ++cc) acc[cc] = 0.0;
    for (int k = lane; k < NMAT; k += 64) {
        float a = A[(size_t)row * NMAT + k];
#pragma unroll
        for (int cc = 0; cc < MRHS; ++cc) acc[cc] += (double)a * (double)W[k * MRHS + cc];
    }
#pragma unroll
    for (int cc = 0; cc < MRHS; ++cc) {
        double v = acc[cc];
#pragma unroll
        for (int off = 32; off > 0; off >>= 1) v += __shfl_xor(v, off);
        if (lane == cc) R[row * MRHS + cc] = (float)(((row == 500 + cc) ? 1.0 : 0.0) - v);
    }
}

// ---------------- single-block LU + solves + 1 IR step (block-synchronous tiles) ----------
// 512 thr = 8 waves. All phases barrier-stepped; per-phase code = R12/R13 proven forms.
__global__ void __launch_bounds__(512) k_lu(float* __restrict__ LU,
                                            float* __restrict__ LUT,
                                            const float* __restrict__ A,
                                            float* __restrict__ dinvG,
                                            float* __restrict__ W,
                                            float* __restrict__ R) {
    __shared__ float piv[2][64];
    __shared__ float U11lds[64 * 65];
    __shared__ float dinvLDS[64];
    __shared__ float yLDS[64 * 65];
    __shared__ float sL21[64 * 65];
    const int tid = threadIdx.x, w = tid >> 6, lane = tid & 63;

    for (int p = 0; p < 8; ++p) {
        const int k0 = p * 64, k1 = k0 + 64, NC = 7 - p;
        panel_body(LU, LUT, dinvG, k0, NC, w, lane, tid, piv, U11lds, dinvLDS);
        __syncthreads();
        for (int ct = 0; ct < NC; ++ct) {
            const int jc0 = k1 + ct * 64;
            // trsm, redundant per wave (R12-proven), lane = column
            float y[64];
#pragma unroll
            for (int i = 0; i < 64; ++i)
                y[i] = LU[(size_t)(k0 + i) * NMAT + jc0 + lane];
#pragma unroll
            for (int tc = 0; tc < 4; ++tc) {
                float cv[16];
#pragma unroll
                for (int q = 0; q < 16; ++q)
                    cv[q] = LUT[(size_t)(k0 + tc * 16 + q) * NMAT + k0 + lane];
#pragma unroll
                for (int q = 0; q < 16; ++q) {
                    const int t = tc * 16 + q;
                    float yt = y[t];
#pragma unroll
                    for (int i = t + 1; i < 64; ++i)
                        y[i] -= rdlane(cv[q], i) * yt;     // literal lane index
                }
            }
            if (w == 0) {
#pragma unroll
                for (int i = 0; i < 64; ++i) yLDS[i * 65 + lane] = y[i];
            }
            __syncthreads();
            // U12^T -> LUT (block copy, R12-proven form)
            for (int idx = tid; idx < 4096; idx += 512) {
                int jc = idx >> 6, i = idx & 63;
                LUT[(size_t)(jc0 + jc) * NMAT + k0 + i] = yLDS[i * 65 + jc];
            }
            // gemm row-tiles, block-synchronous (R13 LDS form, 2x4 per thread @512 thr)
            for (int rt = 0; rt < NC; ++rt) {
                const int r0 = k1 + rt * 64;
                for (int idx = tid; idx < 4096; idx += 512) {
                    int kk = idx >> 6, row = idx & 63;
                    sL21[row * 65 + kk] = LUT[(size_t)(k0 + kk) * NMAT + r0 + row];
                }
                __syncthreads();
                const int trow = tid >> 4, tcol = tid & 15;    // trow 0..31
                float4 v0 = *(const float4*)&LU[(size_t)(r0 + 2 * trow)     * NMAT + jc0 + 4 * tcol];
                float4 v1 = *(const float4*)&LU[(size_t)(r0 + 2 * trow + 1) * NMAT + jc0 + 4 * tcol];
                float c00 = v0.x, c01 = v0.y, c02 = v0.z, c03 = v0.w;
                float c10 = v1.x, c11 = v1.y, c12 = v1.z, c13 = v1.w;
#pragma unroll 4
                for (int kk = 0; kk < 64; ++kk) {
                    float b0 = yLDS[kk * 65 + 4 * tcol + 0];
                    float b1 = yLDS[kk * 65 + 4 * tcol + 1];
                    float b2 = yLDS[kk * 65 + 4 * tcol + 2];
                    float b3 = yLDS[kk * 65 + 4 * tcol + 3];
                    float a_0 = sL21[(2 * trow)     * 65 + kk];
                    float a_1 = sL21[(2 * trow + 1) * 65 + kk];
                    c00 -= a_0 * b0; c01 -= a_0 * b1; c02 -= a_0 * b2; c03 -= a_0 * b3;
                    c10 -= a_1 * b0; c11 -= a_1 * b1; c12 -= a_1 * b2; c13 -= a_1 * b3;
                }
                float4 s0; s0.x = c00; s0.y = c01; s0.z = c02; s0.w = c03;
                float4 s1; s1.x = c10; s1.y = c11; s1.z = c12; s1.w = c13;
                *(float4*)&LU[(size_t)(r0 + 2 * trow)     * NMAT + jc0 + 4 * tcol] = s0;
                *(float4*)&LU[(size_t)(r0 + 2 * trow + 1) * NMAT + jc0 + 4 * tcol] = s1;
                __syncthreads();
            }
        }
        __syncthreads();
    }
    // W = A^{-1} I[:,500:512]
    for (int c = w; c < MRHS; c += 8)
        solve0_f(LUT, dinvG, W, c, lane);
    __syncthreads();
    // 1 IR step (f64 residual) — R14-proven sufficient
    for (int row = w; row < NMAT; row += 8)
        resid_f(A, W, R, row, lane);
    __syncthreads();
    for (int c = w; c < MRHS; c += 8)
        solve1_f(LUT, dinvG, R, W, c, lane);
}

// ---------------- out[i][p] = sum_k W[i][k] * e[k][p] ----------------
__global__ void __launch_bounds__(256) k_out(const float* __restrict__ W,
                                             const float* __restrict__ x,
                                             float* __restrict__ out) {
    const int p4 = blockIdx.x * 256 + threadIdx.x;  // 0..1023
    const int i = blockIdx.y;
    const float4* __restrict__ x4 = (const float4*)x;
    float ax = 0.f, ay = 0.f, az = 0.f, aw = 0.f;
#pragma unroll
    for (int k = 0; k < MRHS; ++k) {
        float w = W[i * MRHS + k];
        float4 v = x4[k * 1024 + p4];
        ax += w * v.x; ay += w * v.y; az += w * v.z; aw += w * v.w;
    }
    float4 o; o.x = ax; o.y = ay; o.z = az; o.w = aw;
    ((float4*)out)[(size_t)i * 1024 + p4] = o;
}

extern "C" void kernel_launch(void* const* d_in, const int* in_sizes, int n_in,
                              void* d_out, int out_size, void* d_ws, size_t ws_size,
                              hipStream_t stream) {
    (void)in_sizes; (void)n_in; (void)out_size; (void)ws_size;
    const float* M     = (const float*)d_in[0];
    const float* r     = (const float*)d_in[1];
    const float* cpart = (const float*)d_in[2];
    const float* x     = (const float*)d_in[3];
    float* out = (float*)d_out;
    float* ws  = (float*)d_ws;

    float* LU   = ws;                 // 262144
    float* A    = ws + 262144;        // 262144
    float* LUT  = ws + 524288;        // 262144
    float* W    = ws + 786432;        // 6144
    float* R    = ws + 792576;        // 6144
    float* dinv = ws + 798720;        // 512

    // 3-dispatch chain
    k_setup<<<dim3(512), 256, 0, stream>>>(M, r, cpart, A, LU);
    k_lu<<<dim3(1), 512, 0, stream>>>(LU, LUT, A, dinv, W, R);
    k_out<<<dim3(4, 512), 256, 0, stream>>>(W, x, out);
}

// Round 17
// 2908.958 us; speedup vs baseline: 3.4569x; 3.4569x over previous
//
#include <hip/hip_runtime.h>
#include <cstddef>

#define NMAT 512
#define MRHS 12

__device__ __forceinline__ float rdlane(float v, int l) {
    return __int_as_float(__builtin_amdgcn_readlane(__float_as_int(v), l));
}

// ---------------- Stage 1: A = LU = constant_part + sum_e r[e] * M[e] ----------------
__global__ void __launch_bounds__(256) k_setup(const float* __restrict__ M,
                                               const float* __restrict__ r,
                                               const float* __restrict__ cpart,
                                               float* __restrict__ A,
                                               float* __restrict__ LU) {
    __shared__ float rs[1024];
    const int tid = threadIdx.x;
    for (int i = tid; i < 1024; i += 256) rs[i] = r[i];
    __syncthreads();
    const int idx2 = blockIdx.x * 256 + tid;          // 0..131071
    const float2* __restrict__ M2 = (const float2*)M;
    float2 a = ((const float2*)cpart)[idx2];
    float ax = a.x, ay = a.y;
#pragma unroll 16
    for (int e = 0; e < 1024; ++e) {
        float2 v = M2[(size_t)e * 131072u + idx2];
        float rv = rs[e];
        ax += rv * v.x; ay += rv * v.y;
    }
    float2 o; o.x = ax; o.y = ay;
    ((float2*)A)[idx2] = o;
    ((float2*)LU)[idx2] = o;
}

// ---------------- LU panel (no pivoting), NB=64, 512 thr = 8 waves (R13-proven) ----------
template <int NR>
__global__ void __launch_bounds__(512) k_panel(const float* __restrict__ LU,
                                               float* __restrict__ LUT,
                                               float* __restrict__ dinvG,
                                               int k0) {
    constexpr int NG = (NR - 64) / 64;   // L21 row-groups
    __shared__ float piv[2][64];
    __shared__ float U11lds[64 * 65];
    __shared__ float dinvLDS[64];
    const int tid = threadIdx.x;
    const int w = tid >> 6, lane = tid & 63;
    const int k1 = k0 + 64;

    float colreg[64];
    if (NG > 0 && w < NG) {
#pragma unroll
        for (int c = 0; c < 64; ++c)
            colreg[c] = LU[(size_t)(k1 + w * 64 + lane) * NMAT + k0 + c];
    }
    float dreg[8];
#pragma unroll
    for (int s = 0; s < 8; ++s)
        dreg[s] = LU[(size_t)(k0 + s * 8 + w) * NMAT + k0 + lane];

    for (int j = 0; j < 64; ++j) {
        if (w == (j & 7)) {
#pragma unroll
            for (int s = 0; s < 8; ++s)
                if ((j >> 3) == s) {
                    piv[j & 1][lane] = dreg[s];
                    U11lds[j * 65 + lane] = dreg[s];
                }
        }
        __syncthreads();
        float pvl = piv[j & 1][lane];
        float pj = __shfl(pvl, j);
        float pinv = 1.0f / pj;
        if (tid == 0) dinvLDS[j] = pinv;
#pragma unroll
        for (int s = 0; s < 8; ++s) {
            int i = s * 8 + w;
            if (i > j) {                        // wave-uniform
                float rv = dreg[s];
                float l = __shfl(rv, j) * pinv;
                float upd = rv - l * pvl;
                rv = (lane > j) ? upd : rv;
                rv = (lane == j) ? l : rv;
                dreg[s] = rv;
            }
        }
    }
    __syncthreads();
    if (w == 0) dinvG[k0 + lane] = dinvLDS[lane];
#pragma unroll
    for (int q = 0; q < 8; ++q) {
        int c = w * 8 + q;
        LUT[(size_t)(k0 + c) * NMAT + k0 + lane] = U11lds[lane * 65 + c];
    }
    if (NG > 0 && w < NG) {
#pragma unroll
        for (int j = 0; j < 64; ++j) {
            float lj = colreg[j] * dinvLDS[j];
            colreg[j] = lj;
            float rowv = U11lds[j * 65 + lane];
#pragma unroll
            for (int jj = j + 1; jj < 64; ++jj)
                colreg[jj] -= lj * rdlane(rowv, jj);
        }
#pragma unroll
        for (int c = 0; c < 64; ++c)
            LUT[(size_t)(k0 + c) * NMAT + k1 + w * 64 + lane] = colreg[c];
    }
}

// ---------------- mode-0 solve (b = e_{500+c}), blocked (R11/R12-proven) ----------------
__device__ __forceinline__ void solve0_f(const float* __restrict__ LUT,
                                         const float* __restrict__ dinv,
                                         float* __restrict__ W, int c, int lane) {
    float y[8];
#pragma unroll
    for (int s = 0; s < 8; ++s) y[s] = 0.f;
    y[7] = (lane == 52 + c) ? 1.0f : 0.0f;
    float Dc[64];
#pragma unroll
    for (int q = 0; q < 64; ++q)
        Dc[q] = LUT[(size_t)(448 + q) * NMAT + 448 + lane];
#pragma unroll 4
    for (int jl = 52; jl < 63; ++jl) {
        float yj = __shfl(y[7], jl);
        if (lane > jl) y[7] -= Dc[jl] * yj;
    }
#pragma unroll
    for (int js = 7; js >= 0; --js) {
        const int base = js * 64;
        float a0 = 0.f, a1 = 0.f;
        for (int s = js + 1; s < 8; ++s) {
#pragma unroll 8
            for (int m = 0; m < 64; m += 2) {
                a0 += LUT[(size_t)(s * 64 + m)     * NMAT + base + lane] * rdlane(y[s], m);
                a1 += LUT[(size_t)(s * 64 + m + 1) * NMAT + base + lane] * rdlane(y[s], m + 1);
            }
        }
        y[js] -= (a0 + a1);
#pragma unroll
        for (int q = 0; q < 64; ++q)
            Dc[q] = LUT[(size_t)(base + q) * NMAT + base + lane];
        float dvb = dinv[base + lane];
#pragma unroll 4
        for (int jl = 63; jl >= 0; --jl) {
            float xj = __shfl(y[js], jl) * rdlane(dvb, jl);
            float t = y[js] - Dc[jl] * xj;
            y[js] = (lane < jl) ? t : ((lane == jl) ? xj : y[js]);
        }
    }
#pragma unroll
    for (int s = 0; s < 8; ++s)
        W[(s * 64 + lane) * MRHS + c] = y[s];
}

// ---------------- last panel (NG=0) + fused mode-0 solves (R12-proven fusion) ------------
__global__ void __launch_bounds__(512) k_panel_last(const float* __restrict__ LU,
                                                    float* __restrict__ LUT,
                                                    float* __restrict__ dinvG,
                                                    float* __restrict__ W) {
    __shared__ float piv[2][64];
    __shared__ float U11lds[64 * 65];
    __shared__ float dinvLDS[64];
    const int tid = threadIdx.x;
    const int w = tid >> 6, lane = tid & 63;
    const int k0 = 448;

    float dreg[8];
#pragma unroll
    for (int s = 0; s < 8; ++s)
        dreg[s] = LU[(size_t)(k0 + s * 8 + w) * NMAT + k0 + lane];
    for (int j = 0; j < 64; ++j) {
        if (w == (j & 7)) {
#pragma unroll
            for (int s = 0; s < 8; ++s)
                if ((j >> 3) == s) {
                    piv[j & 1][lane] = dreg[s];
                    U11lds[j * 65 + lane] = dreg[s];
                }
        }
        __syncthreads();
        float pvl = piv[j & 1][lane];
        float pj = __shfl(pvl, j);
        float pinv = 1.0f / pj;
        if (tid == 0) dinvLDS[j] = pinv;
#pragma unroll
        for (int s = 0; s < 8; ++s) {
            int i = s * 8 + w;
            if (i > j) {
                float rv = dreg[s];
                float l = __shfl(rv, j) * pinv;
                float upd = rv - l * pvl;
                rv = (lane > j) ? upd : rv;
                rv = (lane == j) ? l : rv;
                dreg[s] = rv;
            }
        }
    }
    __syncthreads();
    if (w == 0) dinvG[k0 + lane] = dinvLDS[lane];
#pragma unroll
    for (int q = 0; q < 8; ++q) {
        int c = w * 8 + q;
        LUT[(size_t)(k0 + c) * NMAT + k0 + lane] = U11lds[lane * 65 + c];
    }
    __threadfence_block();
    __syncthreads();
    // LUT complete -> mode-0 solves (this block's own writes + prior dispatches')
    for (int c = w; c < MRHS; c += 8)
        solve0_f(LUT, dinvG, W, c, lane);
}

// ---------------- fused trsm + trailing update (R13-proven VERBATIM) ----------------
__global__ void __launch_bounds__(256) k_update(float* __restrict__ LU,
                                                float* __restrict__ LUT,
                                                int k0) {
    __shared__ float yLDS[64 * 65];
    __shared__ float sL21[64 * 65];
    const int k1 = k0 + 64;
    const int jc0 = k1 + blockIdx.x * 64;
    const int tid = threadIdx.x;
    const int w = tid >> 6, lane = tid & 63;

    float y[64];
#pragma unroll
    for (int i = 0; i < 64; ++i)
        y[i] = LU[(size_t)(k0 + i) * NMAT + jc0 + lane];
#pragma unroll
    for (int tc = 0; tc < 4; ++tc) {
        float cv[16];
#pragma unroll
        for (int q = 0; q < 16; ++q)
            cv[q] = LUT[(size_t)(k0 + tc * 16 + q) * NMAT + k0 + lane];
#pragma unroll
        for (int q = 0; q < 16; ++q) {
            const int t = tc * 16 + q;
            float yt = y[t];
#pragma unroll
            for (int i = t + 1; i < 64; ++i)
                y[i] -= rdlane(cv[q], i) * yt;   // literal lane index
        }
    }

    if (blockIdx.y == 0) {
        if (w == 0) {
#pragma unroll
            for (int i = 0; i < 64; ++i) yLDS[i * 65 + lane] = y[i];
        }
        __syncthreads();
        for (int idx = tid; idx < 4096; idx += 256) {
            int jc = idx >> 6, i = idx & 63;
            LUT[(size_t)(jc0 + jc) * NMAT + k0 + i] = yLDS[i * 65 + jc];
        }
        return;
    }
    const int r0 = k1 + (blockIdx.y - 1) * 64;
    if (w == 0) {
#pragma unroll
        for (int i = 0; i < 64; ++i) yLDS[i * 65 + lane] = y[i];   // yLDS[k][col]
    }
    for (int idx = tid; idx < 4096; idx += 256) {
        int kk = idx >> 6, row = idx & 63;
        sL21[row * 65 + kk] = LUT[(size_t)(k0 + kk) * NMAT + r0 + row];
    }
    __syncthreads();
    const int trow = tid >> 4, tcol = tid & 15;
    float acc[4][4];
#pragma unroll
    for (int rr = 0; rr < 4; ++rr) {
        float4 v = *(const float4*)&LU[(size_t)(r0 + 4 * trow + rr) * NMAT + jc0 + 4 * tcol];
        acc[rr][0] = v.x; acc[rr][1] = v.y; acc[rr][2] = v.z; acc[rr][3] = v.w;
    }
#pragma unroll 4
    for (int kk = 0; kk < 64; ++kk) {
        float b0 = yLDS[kk * 65 + 4 * tcol + 0];
        float b1 = yLDS[kk * 65 + 4 * tcol + 1];
        float b2 = yLDS[kk * 65 + 4 * tcol + 2];
        float b3 = yLDS[kk * 65 + 4 * tcol + 3];
#pragma unroll
        for (int rr = 0; rr < 4; ++rr) {
            float a = sL21[(4 * trow + rr) * 65 + kk];
            acc[rr][0] -= a * b0; acc[rr][1] -= a * b1;
            acc[rr][2] -= a * b2; acc[rr][3] -= a * b3;
        }
    }
#pragma unroll
    for (int rr = 0; rr < 4; ++rr) {
        float4 v; v.x = acc[rr][0]; v.y = acc[rr][1]; v.z = acc[rr][2]; v.w = acc[rr][3];
        *(float4*)&LU[(size_t)(r0 + 4 * trow + rr) * NMAT + jc0 + 4 * tcol] = v;
    }
}

// ---------------- fused residual + mode-1 solve: block c owns column c ----------------
// resid: 4 waves compute R[:,c] (f64) into LDS. solve: wave 0 runs R11-proven blocked
// substitution on it, W[:,c] += x. No cross-block deps.
__global__ void __launch_bounds__(256) k_rs(const float* __restrict__ A,
                                            const float* __restrict__ LUT,
                                            const float* __restrict__ dinv,
                                            float* __restrict__ W) {
    __shared__ float wlds[512];
    __shared__ float rbuf[512];
    const int c = blockIdx.x;
    const int tid = threadIdx.x, w = tid >> 6, lane = tid & 63;
    for (int i = tid; i < 512; i += 256) wlds[i] = W[i * MRHS + c];
    __syncthreads();
    for (int row = w; row < 512; row += 4) {
        double acc = 0.0;
        for (int k = lane; k < 512; k += 64)
            acc += (double)A[(size_t)row * NMAT + k] * (double)wlds[k];
#pragma unroll
        for (int off = 32; off > 0; off >>= 1) acc += __shfl_xor(acc, off);
        if (lane == 0) rbuf[row] = (float)(((row == 500 + c) ? 1.0 : 0.0) - acc);
    }
    __syncthreads();
    if (w != 0) return;
    // blocked forward/backward substitution on rbuf (R11-proven body, B -> rbuf)
    float y[8];
    float Dc[64];
#pragma unroll
    for (int s = 0; s < 8; ++s) y[s] = rbuf[s * 64 + lane];
#pragma unroll
    for (int js = 0; js < 8; ++js) {
        const int base = js * 64;
        float a0 = 0.f, a1 = 0.f;
        for (int s = 0; s < js; ++s) {
#pragma unroll 8
            for (int m = 0; m < 64; m += 2) {
                a0 += LUT[(size_t)(s * 64 + m)     * NMAT + base + lane] * rdlane(y[s], m);
                a1 += LUT[(size_t)(s * 64 + m + 1) * NMAT + base + lane] * rdlane(y[s], m + 1);
            }
        }
        y[js] -= (a0 + a1);
#pragma unroll
        for (int q = 0; q < 64; ++q)
            Dc[q] = LUT[(size_t)(base + q) * NMAT + base + lane];
#pragma unroll 4
        for (int jl = 0; jl < 63; ++jl) {
            float yj = __shfl(y[js], jl);
            if (lane > jl) y[js] -= Dc[jl] * yj;
        }
    }
#pragma unroll
    for (int js = 7; js >= 0; --js) {
        const int base = js * 64;
        float a0 = 0.f, a1 = 0.f;
        for (int s = js + 1; s < 8; ++s) {
#pragma unroll 8
            for (int m = 0; m < 64; m += 2) {
                a0 += LUT[(size_t)(s * 64 + m)     * NMAT + base + lane] * rdlane(y[s], m);
                a1 += LUT[(size_t)(s * 64 + m + 1) * NMAT + base + lane] * rdlane(y[s], m + 1);
            }
        }
        y[js] -= (a0 + a1);
#pragma unroll
        for (int q = 0; q < 64; ++q)
            Dc[q] = LUT[(size_t)(base + q) * NMAT + base + lane];
        float dvb = dinv[base + lane];
#pragma unroll 4
        for (int jl = 63; jl >= 0; --jl) {
            float xj = __shfl(y[js], jl) * rdlane(dvb, jl);
            float t = y[js] - Dc[jl] * xj;
            y[js] = (lane < jl) ? t : ((lane == jl) ? xj : y[js]);
        }
    }
#pragma unroll
    for (int s = 0; s < 8; ++s)
        W[(s * 64 + lane) * MRHS + c] += y[s];
}

// ---------------- out[i][p] = sum_k W[i][k] * e[k][p] ----------------
__global__ void __launch_bounds__(256) k_out(const float* __restrict__ W,
                                             const float* __restrict__ x,
                                             float* __restrict__ out) {
    const int p4 = blockIdx.x * 256 + threadIdx.x;  // 0..1023
    const int i = blockIdx.y;
    const float4* __restrict__ x4 = (const float4*)x;
    float ax = 0.f, ay = 0.f, az = 0.f, aw = 0.f;
#pragma unroll
    for (int k = 0; k < MRHS; ++k) {
        float w = W[i * MRHS + k];
        float4 v = x4[k * 1024 + p4];
        ax += w * v.x; ay += w * v.y; az += w * v.z; aw += w * v.w;
    }
    float4 o; o.x = ax; o.y = ay; o.z = az; o.w = aw;
    ((float4*)out)[(size_t)i * 1024 + p4] = o;
}

extern "C" void kernel_launch(void* const* d_in, const int* in_sizes, int n_in,
                              void* d_out, int out_size, void* d_ws, size_t ws_size,
                              hipStream_t stream) {
    (void)in_sizes; (void)n_in; (void)out_size; (void)ws_size;
    const float* M     = (const float*)d_in[0];
    const float* r     = (const float*)d_in[1];
    const float* cpart = (const float*)d_in[2];
    const float* x     = (const float*)d_in[3];
    float* out = (float*)d_out;
    float* ws  = (float*)d_ws;

    float* LU   = ws;                 // 262144
    float* A    = ws + 262144;        // 262144
    float* LUT  = ws + 524288;        // 262144
    float* W    = ws + 786432;        // 6144
    float* dinv = ws + 798720;        // 512

    // 18-node chain
    k_setup<<<dim3(512), 256, 0, stream>>>(M, r, cpart, A, LU);

    for (int p = 0; p < 7; ++p) {
        const int k0 = p * 64;
        switch (p) {
            case 0: k_panel<512><<<1, 512, 0, stream>>>(LU, LUT, dinv, k0); break;
            case 1: k_panel<448><<<1, 512, 0, stream>>>(LU, LUT, dinv, k0); break;
            case 2: k_panel<384><<<1, 512, 0, stream>>>(LU, LUT, dinv, k0); break;
            case 3: k_panel<320><<<1, 512, 0, stream>>>(LU, LUT, dinv, k0); break;
            case 4: k_panel<256><<<1, 512, 0, stream>>>(LU, LUT, dinv, k0); break;
            case 5: k_panel<192><<<1, 512, 0, stream>>>(LU, LUT, dinv, k0); break;
            case 6: k_panel<128><<<1, 512, 0, stream>>>(LU, LUT, dinv, k0); break;
        }
        const int nc = NMAT - k0 - 64;
        k_update<<<dim3(nc / 64, nc / 64 + 1), 256, 0, stream>>>(LU, LUT, k0);
    }
    k_panel_last<<<1, 512, 0, stream>>>(LU, LUT, dinv, W);   // panel 7 + solve0

    // 1 fused iterative-refinement step
    k_rs<<<dim3(MRHS), 256, 0, stream>>>(A, LUT, dinv, W);

    k_out<<<dim3(4, 512), 256, 0, stream>>>(W, x, out);
}

// Round 18
// 1821.913 us; speedup vs baseline: 5.5195x; 1.5967x over previous
//
#include <hip/hip_runtime.h>
#include <cstddef>

#define NMAT 512
#define MRHS 12

__device__ __forceinline__ float rdlane(float v, int l) {
    return __int_as_float(__builtin_amdgcn_readlane(__float_as_int(v), l));
}

// ---------------- Stage 1: A = LU = constant_part + sum_e r[e] * M[e] ----------------
__global__ void __launch_bounds__(256) k_setup(const float* __restrict__ M,
                                               const float* __restrict__ r,
                                               const float* __restrict__ cpart,
                                               float* __restrict__ A,
                                               float* __restrict__ LU) {
    __shared__ float rs[1024];
    const int tid = threadIdx.x;
    for (int i = tid; i < 1024; i += 256) rs[i] = r[i];
    __syncthreads();
    const int idx2 = blockIdx.x * 256 + tid;          // 0..131071
    const float2* __restrict__ M2 = (const float2*)M;
    float2 a = ((const float2*)cpart)[idx2];
    float ax = a.x, ay = a.y;
#pragma unroll 16
    for (int e = 0; e < 1024; ++e) {
        float2 v = M2[(size_t)e * 131072u + idx2];
        float rv = rs[e];
        ax += rv * v.x; ay += rv * v.y;
    }
    float2 o; o.x = ax; o.y = ay;
    ((float2*)A)[idx2] = o;
    ((float2*)LU)[idx2] = o;
}

// ---------------- LU panel (no pivoting), NB=64, 512 thr = 8 waves (R13-proven) ----------
template <int NR>
__global__ void __launch_bounds__(512) k_panel(const float* __restrict__ LU,
                                               float* __restrict__ LUT,
                                               float* __restrict__ dinvG,
                                               int k0) {
    constexpr int NG = (NR - 64) / 64;   // L21 row-groups
    __shared__ float piv[2][64];
    __shared__ float U11lds[64 * 65];
    __shared__ float dinvLDS[64];
    const int tid = threadIdx.x;
    const int w = tid >> 6, lane = tid & 63;
    const int k1 = k0 + 64;

    float colreg[64];
    if (NG > 0 && w < NG) {
#pragma unroll
        for (int c = 0; c < 64; ++c)
            colreg[c] = LU[(size_t)(k1 + w * 64 + lane) * NMAT + k0 + c];
    }
    float dreg[8];
#pragma unroll
    for (int s = 0; s < 8; ++s)
        dreg[s] = LU[(size_t)(k0 + s * 8 + w) * NMAT + k0 + lane];

    for (int j = 0; j < 64; ++j) {
        if (w == (j & 7)) {
#pragma unroll
            for (int s = 0; s < 8; ++s)
                if ((j >> 3) == s) {
                    piv[j & 1][lane] = dreg[s];
                    U11lds[j * 65 + lane] = dreg[s];
                }
        }
        __syncthreads();
        float pvl = piv[j & 1][lane];
        float pj = __shfl(pvl, j);
        float pinv = 1.0f / pj;
        if (tid == 0) dinvLDS[j] = pinv;
#pragma unroll
        for (int s = 0; s < 8; ++s) {
            int i = s * 8 + w;
            if (i > j) {                        // wave-uniform
                float rv = dreg[s];
                float l = __shfl(rv, j) * pinv;
                float upd = rv - l * pvl;
                rv = (lane > j) ? upd : rv;
                rv = (lane == j) ? l : rv;
                dreg[s] = rv;
            }
        }
    }
    __syncthreads();
    if (w == 0) dinvG[k0 + lane] = dinvLDS[lane];
#pragma unroll
    for (int q = 0; q < 8; ++q) {
        int c = w * 8 + q;
        LUT[(size_t)(k0 + c) * NMAT + k0 + lane] = U11lds[lane * 65 + c];
    }
    if (NG > 0 && w < NG) {
#pragma unroll
        for (int j = 0; j < 64; ++j) {
            float lj = colreg[j] * dinvLDS[j];
            colreg[j] = lj;
            float rowv = U11lds[j * 65 + lane];
#pragma unroll
            for (int jj = j + 1; jj < 64; ++jj)
                colreg[jj] -= lj * rdlane(rowv, jj);
        }
#pragma unroll
        for (int c = 0; c < 64; ++c)
            LUT[(size_t)(k0 + c) * NMAT + k1 + w * 64 + lane] = colreg[c];
    }
}

// ---------------- fused trsm + trailing update (R13-proven; full VGPR budget) -------------
__global__ void __launch_bounds__(256, 1) k_update(float* __restrict__ LU,
                                                   float* __restrict__ LUT,
                                                   int k0) {
    __shared__ float yLDS[64 * 65];
    __shared__ float sL21[64 * 65];
    const int k1 = k0 + 64;
    const int jc0 = k1 + blockIdx.x * 64;
    const int tid = threadIdx.x;
    const int w = tid >> 6, lane = tid & 63;

    float y[64];
#pragma unroll
    for (int i = 0; i < 64; ++i)
        y[i] = LU[(size_t)(k0 + i) * NMAT + jc0 + lane];
#pragma unroll
    for (int tc = 0; tc < 4; ++tc) {
        float cv[16];
#pragma unroll
        for (int q = 0; q < 16; ++q)
            cv[q] = LUT[(size_t)(k0 + tc * 16 + q) * NMAT + k0 + lane];
#pragma unroll
        for (int q = 0; q < 16; ++q) {
            const int t = tc * 16 + q;
            float yt = y[t];
#pragma unroll
            for (int i = t + 1; i < 64; ++i)
                y[i] -= rdlane(cv[q], i) * yt;   // literal lane index
        }
    }

    if (blockIdx.y == 0) {
        if (w == 0) {
#pragma unroll
            for (int i = 0; i < 64; ++i) yLDS[i * 65 + lane] = y[i];
        }
        __syncthreads();
        for (int idx = tid; idx < 4096; idx += 256) {
            int jc = idx >> 6, i = idx & 63;
            LUT[(size_t)(jc0 + jc) * NMAT + k0 + i] = yLDS[i * 65 + jc];
        }
        return;
    }
    const int r0 = k1 + (blockIdx.y - 1) * 64;
    if (w == 0) {
#pragma unroll
        for (int i = 0; i < 64; ++i) yLDS[i * 65 + lane] = y[i];   // yLDS[k][col]
    }
    for (int idx = tid; idx < 4096; idx += 256) {
        int kk = idx >> 6, row = idx & 63;
        sL21[row * 65 + kk] = LUT[(size_t)(k0 + kk) * NMAT + r0 + row];
    }
    __syncthreads();
    const int trow = tid >> 4, tcol = tid & 15;
    float acc[4][4];
#pragma unroll
    for (int rr = 0; rr < 4; ++rr) {
        float4 v = *(const float4*)&LU[(size_t)(r0 + 4 * trow + rr) * NMAT + jc0 + 4 * tcol];
        acc[rr][0] = v.x; acc[rr][1] = v.y; acc[rr][2] = v.z; acc[rr][3] = v.w;
    }
#pragma unroll 4
    for (int kk = 0; kk < 64; ++kk) {
        float b0 = yLDS[kk * 65 + 4 * tcol + 0];
        float b1 = yLDS[kk * 65 + 4 * tcol + 1];
        float b2 = yLDS[kk * 65 + 4 * tcol + 2];
        float b3 = yLDS[kk * 65 + 4 * tcol + 3];
#pragma unroll
        for (int rr = 0; rr < 4; ++rr) {
            float a = sL21[(4 * trow + rr) * 65 + kk];
            acc[rr][0] -= a * b0; acc[rr][1] -= a * b1;
            acc[rr][2] -= a * b2; acc[rr][3] -= a * b3;
        }
    }
#pragma unroll
    for (int rr = 0; rr < 4; ++rr) {
        float4 v; v.x = acc[rr][0]; v.y = acc[rr][1]; v.z = acc[rr][2]; v.w = acc[rr][3];
        *(float4*)&LU[(size_t)(r0 + 4 * trow + rr) * NMAT + jc0 + 4 * tcol] = v;
    }
}

// ---------------- BLOCKED triangular solves (R11/R13-proven; constant-index readlane) -----
__global__ void __launch_bounds__(64) k_solve(const float* __restrict__ LUT,
                                              const float* __restrict__ dinv,
                                              const float* __restrict__ B,
                                              float* __restrict__ W, int mode) {
    const int c = blockIdx.x;
    const int lane = threadIdx.x;
    float y[8];
    float Dc[64];
    if (mode) {
#pragma unroll
        for (int s = 0; s < 8; ++s) y[s] = B[(s * 64 + lane) * MRHS + c];
#pragma unroll
        for (int js = 0; js < 8; ++js) {
            const int base = js * 64;
            float a0 = 0.f, a1 = 0.f;
            for (int s = 0; s < js; ++s) {
#pragma unroll 8
                for (int m = 0; m < 64; m += 2) {
                    a0 += LUT[(size_t)(s * 64 + m)     * NMAT + base + lane] * rdlane(y[s], m);
                    a1 += LUT[(size_t)(s * 64 + m + 1) * NMAT + base + lane] * rdlane(y[s], m + 1);
                }
            }
            y[js] -= (a0 + a1);
#pragma unroll
            for (int q = 0; q < 64; ++q)
                Dc[q] = LUT[(size_t)(base + q) * NMAT + base + lane];
#pragma unroll 4
            for (int jl = 0; jl < 63; ++jl) {
                float yj = __shfl(y[js], jl);
                if (lane > jl) y[js] -= Dc[jl] * yj;
            }
        }
    } else {
#pragma unroll
        for (int s = 0; s < 8; ++s) y[s] = 0.f;
        y[7] = (lane == 52 + c) ? 1.0f : 0.0f;
#pragma unroll
        for (int q = 0; q < 64; ++q)
            Dc[q] = LUT[(size_t)(448 + q) * NMAT + 448 + lane];
#pragma unroll 4
        for (int jl = 52; jl < 63; ++jl) {
            float yj = __shfl(y[7], jl);
            if (lane > jl) y[7] -= Dc[jl] * yj;
        }
    }
    // blocked backward: U x = y
#pragma unroll
    for (int js = 7; js >= 0; --js) {
        const int base = js * 64;
        float a0 = 0.f, a1 = 0.f;
        for (int s = js + 1; s < 8; ++s) {
#pragma unroll 8
            for (int m = 0; m < 64; m += 2) {
                a0 += LUT[(size_t)(s * 64 + m)     * NMAT + base + lane] * rdlane(y[s], m);
                a1 += LUT[(size_t)(s * 64 + m + 1) * NMAT + base + lane] * rdlane(y[s], m + 1);
            }
        }
        y[js] -= (a0 + a1);
#pragma unroll
        for (int q = 0; q < 64; ++q)
            Dc[q] = LUT[(size_t)(base + q) * NMAT + base + lane];
        float dvb = dinv[base + lane];
#pragma unroll 4
        for (int jl = 63; jl >= 0; --jl) {
            float xj = __shfl(y[js], jl) * rdlane(dvb, jl);
            float t = y[js] - Dc[jl] * xj;
            y[js] = (lane < jl) ? t : ((lane == jl) ? xj : y[js]);
        }
    }
#pragma unroll
    for (int s = 0; s < 8; ++s) {
        int row = s * 64 + lane;
        if (mode) W[row * MRHS + c] += y[s];
        else      W[row * MRHS + c] = y[s];
    }
}

// ---------------- residual R = I[:,500:512] - A @ W  (f64 accumulate) ----------------
__global__ void __launch_bounds__(64) k_resid(const float* __restrict__ A,
                                              const float* __restrict__ W,
                                              float* __restrict__ R) {
    const int row = blockIdx.x;
    const int lane = threadIdx.x;
    double acc[MRHS];
#pragma unroll
    for (int cc = 0; cc < MRHS; ++cc) acc[cc] = 0.0;
    for (int k = lane; k < NMAT; k += 64) {
        float a = A[(size_t)row * NMAT + k];
#pragma unroll
        for (int cc = 0; cc < MRHS; ++cc) acc[cc] += (double)a * (double)W[k * MRHS + cc];
    }
#pragma unroll
    for (int cc = 0; cc < MRHS; ++cc) {
        double v = acc[cc];
#pragma unroll
        for (int off = 32; off > 0; off >>= 1) v += __shfl_xor(v, off);
        if (lane == cc) R[row * MRHS + cc] = (float)(((row == 500 + cc) ? 1.0 : 0.0) - v);
    }
}

// ---------------- out[i][p] = sum_k W[i][k] * e[k][p] ----------------
__global__ void __launch_bounds__(256) k_out(const float* __restrict__ W,
                                             const float* __restrict__ x,
                                             float* __restrict__ out) {
    const int p4 = blockIdx.x * 256 + threadIdx.x;  // 0..1023
    const int i = blockIdx.y;
    const float4* __restrict__ x4 = (const float4*)x;
    float ax = 0.f, ay = 0.f, az = 0.f, aw = 0.f;
#pragma unroll
    for (int k = 0; k < MRHS; ++k) {
        float w = W[i * MRHS + k];
        float4 v = x4[k * 1024 + p4];
        ax += w * v.x; ay += w * v.y; az += w * v.z; aw += w * v.w;
    }
    float4 o; o.x = ax; o.y = ay; o.z = az; o.w = aw;
    ((float4*)out)[(size_t)i * 1024 + p4] = o;
}

extern "C" void kernel_launch(void* const* d_in, const int* in_sizes, int n_in,
                              void* d_out, int out_size, void* d_ws, size_t ws_size,
                              hipStream_t stream) {
    (void)in_sizes; (void)n_in; (void)out_size; (void)ws_size;
    const float* M     = (const float*)d_in[0];
    const float* r     = (const float*)d_in[1];
    const float* cpart = (const float*)d_in[2];
    const float* x     = (const float*)d_in[3];
    float* out = (float*)d_out;
    float* ws  = (float*)d_ws;

    float* LU   = ws;                 // 262144
    float* A    = ws + 262144;        // 262144
    float* LUT  = ws + 524288;        // 262144
    float* W    = ws + 786432;        // 6144
    float* R    = ws + 792576;        // 6144
    float* dinv = ws + 798720;        // 512

    // 20-node chain
    k_setup<<<dim3(512), 256, 0, stream>>>(M, r, cpart, A, LU);

    for (int p = 0; p < 8; ++p) {
        const int k0 = p * 64;
        switch (p) {
            case 0: k_panel<512><<<1, 512, 0, stream>>>(LU, LUT, dinv, k0); break;
            case 1: k_panel<448><<<1, 512, 0, stream>>>(LU, LUT, dinv, k0); break;
            case 2: k_panel<384><<<1, 512, 0, stream>>>(LU, LUT, dinv, k0); break;
            case 3: k_panel<320><<<1, 512, 0, stream>>>(LU, LUT, dinv, k0); break;
            case 4: k_panel<256><<<1, 512, 0, stream>>>(LU, LUT, dinv, k0); break;
            case 5: k_panel<192><<<1, 512, 0, stream>>>(LU, LUT, dinv, k0); break;
            case 6: k_panel<128><<<1, 512, 0, stream>>>(LU, LUT, dinv, k0); break;
            case 7: k_panel< 64><<<1, 512, 0, stream>>>(LU, LUT, dinv, k0); break;
        }
        const int nc = NMAT - k0 - 64;
        if (nc > 0)
            k_update<<<dim3(nc / 64, nc / 64 + 1), 256, 0, stream>>>(LU, LUT, k0);
    }

    // Stage 3: W = A^{-1} I[:,500:512], + 1 iterative-refinement step (R14-proven)
    k_solve<<<dim3(MRHS), 64, 0, stream>>>(LUT, dinv, R /*unused*/, W, 0);
    k_resid<<<dim3(NMAT), 64, 0, stream>>>(A, W, R);
    k_solve<<<dim3(MRHS), 64, 0, stream>>>(LUT, dinv, R, W, 1);

    // Stage 4: out = W @ e
    k_out<<<dim3(4, 512), 256, 0, stream>>>(W, x, out);
}